// Round 13
// baseline (18761.765 us; speedup 1.0000x reference)
//
#include <hip/hip_runtime.h>

typedef unsigned short ushort_t;
typedef unsigned int uint_t;
typedef __attribute__((ext_vector_type(8))) short short8;
typedef __attribute__((ext_vector_type(4))) float f32x4;
typedef __attribute__((ext_vector_type(4))) uint_t uint4v;

// ---------------- workspace layout (bytes) ----------------
constexpr size_t OFF_WSFT  = 0;                           // bf16 [512][512] (n,k)
constexpr size_t OFF_WAFT  = OFF_WSFT  + 512*512*2;
constexpr size_t OFF_WO1AT = OFF_WAFT  + 512*512*2;       // W_o1 rows 0..511
constexpr size_t OFF_WO1BT = OFF_WO1AT + 512*512*2;       // W_o1 rows 512..1023
constexpr size_t OFF_WAST  = OFF_WO1BT + 512*512*2;       // W_as top
constexpr size_t OFF_WSST  = OFF_WAST  + 512*512*2;       // W_ss top
constexpr size_t OFF_GAPS  = OFF_WSST  + 512*512*2;       // f32 [200][512]
constexpr size_t OFF_CAFV  = OFF_GAPS  + 200*512*4;       // f32 [512]
constexpr size_t OFF_XA    = OFF_CAFV  + 512*4;           // f32 [600][512]
constexpr size_t OFF_XS    = OFF_XA    + 600*512*4;       // f32 [600][512]
constexpr size_t OFF_PROJ  = OFF_XS    + 600*512*4;       // f32 [300][512]
constexpr size_t OFF_ASG   = OFF_PROJ  + 300*512*4;       // bf16 [512][512] (unused by rekt_all now)
constexpr size_t OFF_ISKR  = OFF_ASG   + 512*512*2;       // i32 [199][512] gather row (b*199+tl)
constexpr size_t OFF_IGAP  = OFF_ISKR  + 199*512*4;
constexpr size_t OFF_IXR   = OFF_IGAP  + 199*512*4;
constexpr size_t OFF_ISK   = OFF_IXR   + 199*512*4;
constexpr size_t OFF_DEP   = OFF_ISK   + 199*512*4;       // i32 [199][512] dependency depth
constexpr size_t OFF_LCNT  = OFF_DEP   + 199*512*4;       // i32 [16]
constexpr size_t OFF_LROW  = OFF_LCNT  + 16*4;            // u32 [12][101888] round lists
constexpr size_t OFF_FLG   = OFF_LROW  + (size_t)12*101888*4; // i32 [16][8] (unused now)
constexpr size_t OFF_HS    = OFF_FLG   + 16*8*4;          // bf16 [512*199][512]  hs = LS@Wo1B
constexpr size_t OFF_SKB   = OFF_HS    + (size_t)101888*512*2; // bf16 [512*199][512]
constexpr size_t WS_NEED   = OFF_SKB   + (size_t)101888*512*2; // ~213 MB

constexpr int NROWS = 199 * 512;
constexpr int ROUNDS = 12;

__device__ __forceinline__ ushort_t f2bf(float f) {
  union { float f; uint_t u; } v; v.f = f;
  uint_t u = v.u;
  return (ushort_t)((u + 0x7FFFu + ((u >> 16) & 1u)) >> 16);
}
__device__ __forceinline__ float bf2f(ushort_t h) {
  union { uint_t u; float f; } v; v.u = ((uint_t)h) << 16;
  return v.f;
}

#define MFMA(a, b, c) __builtin_amdgcn_mfma_f32_16x16x32_bf16((a), (b), (c), 0, 0, 0)

// ---------------- prologue ----------------
__global__ void rekt_prep(const float* __restrict__ ls_state, const float* __restrict__ skill_state0,
                          const float* __restrict__ W_sf, const float* __restrict__ W_af,
                          const float* __restrict__ W_ss, const float* __restrict__ W_as,
                          const float* __restrict__ W_o1,
                          float* __restrict__ d_out, char* __restrict__ ws) {
  ushort_t* WSFT  = (ushort_t*)(ws + OFF_WSFT);
  ushort_t* WAFT  = (ushort_t*)(ws + OFF_WAFT);
  ushort_t* WO1AT = (ushort_t*)(ws + OFF_WO1AT);
  ushort_t* WO1BT = (ushort_t*)(ws + OFF_WO1BT);
  ushort_t* WAST  = (ushort_t*)(ws + OFF_WAST);
  ushort_t* WSST  = (ushort_t*)(ws + OFF_WSST);
  int*      LCNT  = (int*)(ws + OFF_LCNT);
  ushort_t* SKB   = (ushort_t*)(ws + OFF_SKB);

  const size_t t0 = (size_t)blockIdx.x * blockDim.x + threadIdx.x;
  const size_t st = (size_t)gridDim.x * blockDim.x;

  for (size_t i = t0; i < 512*512; i += st) {
    const int k = (int)(i >> 9), n = (int)(i & 511);
    const size_t d = (size_t)n * 512 + k;
    WSFT[d]  = f2bf(W_sf[i]);
    WAFT[d]  = f2bf(W_af[i]);
    WAST[d]  = f2bf(W_as[i]);
    WSST[d]  = f2bf(W_ss[i]);
    WO1AT[d] = f2bf(W_o1[i]);
    WO1BT[d] = f2bf(W_o1[i + (size_t)512*512]);
  }
  for (size_t i = t0; i < 512*512; i += st) {
    const size_t b = i >> 9, n = i & 511;
    SKB[(b * 199) * 512 + n] = f2bf(skill_state0[n]);
  }
  for (size_t i = t0; i < (size_t)512*199; i += st) d_out[i] = 0.f;
  for (size_t i = t0; i < 16; i += st) LCNT[i] = 0;
}

// ---------------- tables ----------------
__global__ void rekt_tab(const float* __restrict__ se, const float* __restrict__ ae,
                         const float* __restrict__ te,
                         const float* __restrict__ W_sf, const float* __restrict__ b_sf,
                         const float* __restrict__ W_af, const float* __restrict__ b_af,
                         const float* __restrict__ W_ss, const float* __restrict__ b_ss,
                         const float* __restrict__ W_as, const float* __restrict__ b_as,
                         const float* __restrict__ W_o1, const float* __restrict__ b_o1,
                         char* __restrict__ ws) {
  __shared__ float ar[512];
  const int n = threadIdx.x;
  const int bid = blockIdx.x;
  const float* W; const float* bias; float* dst;
  if (bid < 600) {
    const int a = bid / 300, sk = bid % 300;
    ar[n] = se[(size_t)sk*512 + n] + ae[(size_t)a*512 + n];
    W = W_as + (size_t)512*512; bias = b_as; dst = (float*)(ws + OFF_XA) + (size_t)bid*512;
  } else if (bid < 1200) {
    const int r = bid - 600, a = r / 300, sk = r % 300;
    ar[n] = se[(size_t)sk*512 + n] + ae[(size_t)a*512 + n];
    W = W_ss + (size_t)512*512; bias = b_ss; dst = (float*)(ws + OFF_XS) + (size_t)r*512;
  } else if (bid < 1500) {
    const int r = bid - 1200;
    ar[n] = se[(size_t)r*512 + n];
    W = W_o1 + (size_t)1024*512; bias = b_o1; dst = (float*)(ws + OFF_PROJ) + (size_t)r*512;
  } else if (bid < 1700) {
    const int t = bid - 1500;
    ar[n] = te[(size_t)t*512 + n];
    W = W_sf + (size_t)512*512; bias = b_sf; dst = (float*)(ws + OFF_GAPS) + (size_t)t*512;
  } else {
    ar[n] = te[512 + n];
    W = W_af + (size_t)512*512; bias = b_af; dst = (float*)(ws + OFF_CAFV);
  }
  __syncthreads();
  float acc = bias[n];
  for (int k = 0; k < 512; ++k) acc = fmaf(ar[k], W[(size_t)k*512 + n], acc);
  dst[n] = acc;
}

// ---------------- per-step indices + dependency depth ----------------
__global__ void rekt_idx(const int* __restrict__ next_skill, const int* __restrict__ next_ans,
                         char* __restrict__ ws) {
  int* ISKR = (int*)(ws + OFF_ISKR);
  int* IGAP = (int*)(ws + OFF_IGAP);
  int* IXR  = (int*)(ws + OFF_IXR);
  int* ISK  = (int*)(ws + OFF_ISK);
  int* DEP  = (int*)(ws + OFF_DEP);
  __shared__ int lt[300];
  __shared__ int pd[199];
  const int b = blockIdx.x;
  for (int i = threadIdx.x; i < 300; i += blockDim.x) lt[i] = 0;
  __syncthreads();
  if (threadIdx.x == 0) {
    for (int s = 0; s < 199; ++s) {
      const int sk = next_skill[b * 199 + s];
      const int tl = lt[sk];
      ISKR[s * 512 + b] = b * 199 + tl;
      IGAP[s * 512 + b] = s - tl;
      IXR [s * 512 + b] = next_ans[b * 199 + s] * 300 + sk;
      ISK [s * 512 + b] = sk;
      const int d = (s == 0) ? 0 : (pd[tl] + 1);
      pd[s] = d;
      DEP[s * 512 + b] = d;
      lt[sk] = s;
    }
  }
}

// ---------------- round lists ----------------
__global__ void rekt_lists(char* __restrict__ ws) {
  const int* DEP = (const int*)(ws + OFF_DEP);
  int* LCNT = (int*)(ws + OFF_LCNT);
  uint_t* LROW = (uint_t*)(ws + OFF_LROW);
  const int i = blockIdx.x * blockDim.x + threadIdx.x;
  if (i < NROWS) {
    const int s = i >> 9, b = i & 511;
    int d = DEP[i];
    if (d > ROUNDS - 1) d = ROUNDS - 1;
    const int pos = atomicAdd(&LCNT[d], 1);
    LROW[(size_t)d * NROWS + pos] = ((uint_t)s << 16) | (uint_t)b;
  }
}

// ---------------- skill rounds (unchanged from round 12; proven) ----------------
__global__ __launch_bounds__(512, 1) void rekt_skill(int round, char* __restrict__ ws) {
  const ushort_t* WSFT  = (const ushort_t*)(ws + OFF_WSFT);
  const ushort_t* WSST  = (const ushort_t*)(ws + OFF_WSST);
  const ushort_t* WO1BT = (const ushort_t*)(ws + OFF_WO1BT);
  const float* GAPS = (const float*)(ws + OFF_GAPS);
  const float* XS   = (const float*)(ws + OFF_XS);
  const int* ISKR = (const int*)(ws + OFF_ISKR);
  const int* IGAP = (const int*)(ws + OFF_IGAP);
  const int* IXR  = (const int*)(ws + OFF_IXR);
  const int* LCNT = (const int*)(ws + OFF_LCNT);
  const uint_t* LROW = (const uint_t*)(ws + OFF_LROW) + (size_t)round * NROWS;
  ushort_t* HS  = (ushort_t*)(ws + OFF_HS);
  ushort_t* SKB = (ushort_t*)(ws + OFF_SKB);

  __shared__ __align__(16) short Ta[32 * 512];
  __shared__ __align__(16) short LSb[32 * 512];
  __shared__ int gap_s[32], xr_s[32], skrow_s[32], dst_s[32];

  const int nrows = LCNT[round];
  const int ntiles = (nrows + 31) >> 5;
  const int tid = threadIdx.x;
  const int lane = tid & 63, w = tid >> 6;
  const int cc = lane & 15, hi = lane >> 4;
  const int aswz = (cc & 7) << 3;

  for (int tile = blockIdx.x; tile < ntiles; tile += gridDim.x) {
    if (tid < 32) {
      int idx = tile * 32 + tid;
      if (idx >= nrows) idx = nrows - 1;
      const uint_t rid = LROW[idx];
      const int s = (int)(rid >> 16), b = (int)(rid & 0xffff);
      const int o = s * 512 + b;
      gap_s[tid] = IGAP[o];
      xr_s[tid]  = IXR[o];
      skrow_s[tid] = ISKR[o];
      dst_s[tid] = b * 199 + s;
    }
    __syncthreads();

#pragma unroll
    for (int t = 0; t < 4; ++t) {
      const int i = t * 512 + tid;
      const int r = i >> 6, gi = i & 63;
      const uint4v v = *reinterpret_cast<const uint4v*>(SKB + (size_t)skrow_s[r] * 512 + gi * 8);
      *reinterpret_cast<uint4v*>(Ta + r * 512 + ((gi ^ (r & 7)) << 3)) = v;
    }
    __syncthreads();

#pragma unroll
    for (int t = 0; t < 4; ++t) {
      const int col = w * 64 + t * 16 + cc;
      const ushort_t* bp = WSFT + (size_t)col * 512 + hi * 8;
      f32x4 a0 = {0.f,0.f,0.f,0.f}, a1 = {0.f,0.f,0.f,0.f};
#pragma unroll
      for (int j = 0; j < 16; ++j) {
        const short8 b8 = *reinterpret_cast<const short8*>(bp + j * 32);
        const int go = ((j * 4 + hi) << 3) ^ aswz;
        a0 = MFMA(*reinterpret_cast<const short8*>(Ta + cc * 512 + go), b8, a0);
        a1 = MFMA(*reinterpret_cast<const short8*>(Ta + (16 + cc) * 512 + go), b8, a1);
      }
#pragma unroll
      for (int m = 0; m < 2; ++m) {
        const f32x4 acc = m ? a1 : a0;
#pragma unroll
        for (int q = 0; q < 4; ++q) {
          const int r = m * 16 + hi * 4 + q;
          const int si = r * 512 + ((((col >> 3) ^ (r & 7)) << 3) | (col & 7));
          const float F = acc[q] + GAPS[(size_t)gap_s[r] * 512 + col];
          const float ls = bf2f((ushort_t)Ta[si]) * (1.f / (1.f + __expf(-F)));
          const uint_t pz = f2bf(ls);
          const uint_t oz = (uint_t)__shfl_xor((int)pz, 1, 64);
          if (!(cc & 1)) *reinterpret_cast<uint_t*>(LSb + si) = pz | (oz << 16);
        }
      }
    }
    __syncthreads();

#pragma unroll
    for (int t = 0; t < 4; ++t) {
      const int col = w * 64 + t * 16 + cc;
      const ushort_t* bp2 = WSST  + (size_t)col * 512 + hi * 8;
      const ushort_t* bp3 = WO1BT + (size_t)col * 512 + hi * 8;
      f32x4 n0 = {0.f,0.f,0.f,0.f}, n1 = n0, h0 = n0, h1 = n0;
#pragma unroll
      for (int j = 0; j < 16; ++j) {
        const int go = ((j * 4 + hi) << 3) ^ aswz;
        const short8 a0 = *reinterpret_cast<const short8*>(LSb + cc * 512 + go);
        const short8 a1 = *reinterpret_cast<const short8*>(LSb + (16 + cc) * 512 + go);
        const short8 b2 = *reinterpret_cast<const short8*>(bp2 + j * 32);
        const short8 b3 = *reinterpret_cast<const short8*>(bp3 + j * 32);
        n0 = MFMA(a0, b2, n0); n1 = MFMA(a1, b2, n1);
        h0 = MFMA(a0, b3, h0); h1 = MFMA(a1, b3, h1);
      }
#pragma unroll
      for (int m = 0; m < 2; ++m) {
        const f32x4 nn = m ? n1 : n0;
        const f32x4 hh = m ? h1 : h0;
#pragma unroll
        for (int q = 0; q < 4; ++q) {
          const int r = m * 16 + hi * 4 + q;
          const int si = r * 512 + ((((col >> 3) ^ (r & 7)) << 3) | (col & 7));
          float y = nn[q] + XS[(size_t)xr_s[r] * 512 + col];
          y = fminf(fmaxf(y, -12.f), 12.f);
          const float e = __expf(2.f * y);
          const float skv = bf2f((ushort_t)LSb[si]) + (e - 1.f) / (e + 1.f);
          const uint_t pz = f2bf(skv);
          const uint_t oz = (uint_t)__shfl_xor((int)pz, 1, 64);
          const uint_t hz = f2bf(hh[q]);
          const uint_t ho = (uint_t)__shfl_xor((int)hz, 1, 64);
          if (!(cc & 1)) {
            *reinterpret_cast<uint_t*>(SKB + (size_t)dst_s[r] * 512 + col) = pz | (oz << 16);
            *reinterpret_cast<uint_t*>(HS  + (size_t)dst_s[r] * 512 + col) = hz | (ho << 16);
          }
        }
      }
    }
    __syncthreads();
  }
}

// ---------------- all-path: 16 block-private scans, ZERO global sync ----------------
// Block g owns batches g*32..g*32+31 end-to-end.  AS lives in LDS for all 199 steps.
// Per step: phase A (AS@Waf -> LA, LDS) | syncthreads | phase B (na/ha; AS'->LDS;
// P = relu(ha + HS + PROJ) . w_o2 partial -> atomicAdd).  Weights stream from L2 (1.5 MB).
__global__ __launch_bounds__(512, 1) void rekt_all(
    const float* __restrict__ ls_state, const float* __restrict__ w_o2,
    float* __restrict__ d_out, char* __restrict__ ws) {

  const ushort_t* WAFT  = (const ushort_t*)(ws + OFF_WAFT);
  const ushort_t* WO1AT = (const ushort_t*)(ws + OFF_WO1AT);
  const ushort_t* WAST  = (const ushort_t*)(ws + OFF_WAST);
  const float* CAFV = (const float*)(ws + OFF_CAFV);
  const float* XA   = (const float*)(ws + OFF_XA);
  const float* PROJ = (const float*)(ws + OFF_PROJ);
  const int* IXR = (const int*)(ws + OFF_IXR);
  const int* ISK = (const int*)(ws + OFF_ISK);
  const ushort_t* HS = (const ushort_t*)(ws + OFF_HS);

  __shared__ __align__(16) short ASb[32 * 512];
  __shared__ __align__(16) short LAb[32 * 512];
  __shared__ int xr_s[32], sk_s[32];

  const int tid = threadIdx.x;
  const int lane = tid & 63, w = tid >> 6;
  const int cc = lane & 15, hi = lane >> 4;
  const int b0 = blockIdx.x << 5;
  const int aswz = (cc & 7) << 3;

  float wo2v[4], cafv4[4];
#pragma unroll
  for (int t = 0; t < 4; ++t) {
    const int col = w * 64 + t * 16 + cc;
    wo2v[t] = w_o2[col];
    cafv4[t] = CAFV[col];
  }

  // init ASb rows = bf16(ls_state), swizzled
  for (int i = tid; i < 2048; i += 512) {
    const int r = i >> 6, gi = i & 63;
    uint_t pk0 = (uint_t)f2bf(ls_state[gi*8+0]) | ((uint_t)f2bf(ls_state[gi*8+1]) << 16);
    uint_t pk1 = (uint_t)f2bf(ls_state[gi*8+2]) | ((uint_t)f2bf(ls_state[gi*8+3]) << 16);
    uint_t pk2 = (uint_t)f2bf(ls_state[gi*8+4]) | ((uint_t)f2bf(ls_state[gi*8+5]) << 16);
    uint_t pk3 = (uint_t)f2bf(ls_state[gi*8+6]) | ((uint_t)f2bf(ls_state[gi*8+7]) << 16);
    uint4v v = {pk0, pk1, pk2, pk3};
    *reinterpret_cast<uint4v*>(ASb + r * 512 + ((gi ^ (r & 7)) << 3)) = v;
  }
  __syncthreads();

  for (int s = 0; s < 199; ++s) {
    if (tid < 32) {
      const int o = s * 512 + b0 + tid;
      xr_s[tid] = IXR[o];
      sk_s[tid] = ISK[o];
    }

    // ---- phase A: G = AS@Waf; LA = AS*sig(G+CAF) -> LAb ----
#pragma unroll
    for (int t = 0; t < 4; ++t) {
      const int col = w * 64 + t * 16 + cc;
      const ushort_t* bp = WAFT + (size_t)col * 512 + hi * 8;
      f32x4 a0 = {0.f,0.f,0.f,0.f}, a1 = {0.f,0.f,0.f,0.f};
#pragma unroll
      for (int j = 0; j < 16; ++j) {
        const short8 b8 = *reinterpret_cast<const short8*>(bp + j * 32);
        const int go = ((j * 4 + hi) << 3) ^ aswz;
        a0 = MFMA(*reinterpret_cast<const short8*>(ASb + cc * 512 + go), b8, a0);
        a1 = MFMA(*reinterpret_cast<const short8*>(ASb + (16 + cc) * 512 + go), b8, a1);
      }
#pragma unroll
      for (int m = 0; m < 2; ++m) {
        const f32x4 acc = m ? a1 : a0;
#pragma unroll
        for (int q = 0; q < 4; ++q) {
          const int r = m * 16 + hi * 4 + q;
          const int si = r * 512 + ((((col >> 3) ^ (r & 7)) << 3) | (col & 7));
          const float G = acc[q] + cafv4[t];
          const float la = bf2f((ushort_t)ASb[si]) * (1.f / (1.f + __expf(-G)));
          const uint_t pz = f2bf(la);
          const uint_t oz = (uint_t)__shfl_xor((int)pz, 1, 64);
          if (!(cc & 1)) *reinterpret_cast<uint_t*>(LAb + si) = pz | (oz << 16);
        }
      }
    }
    __syncthreads();                  // LAb ready; indices published; ASb free to overwrite

    // ---- phase B: na = LA@Was, ha = LA@Wo1A; AS' -> ASb; P partial ----
    float pv[2][4] = {{0.f,0.f,0.f,0.f},{0.f,0.f,0.f,0.f}};
#pragma unroll
    for (int t = 0; t < 4; ++t) {
      const int col = w * 64 + t * 16 + cc;
      const ushort_t* bpN = WAST  + (size_t)col * 512 + hi * 8;
      const ushort_t* bpH = WO1AT + (size_t)col * 512 + hi * 8;
      f32x4 n0 = {0.f,0.f,0.f,0.f}, n1 = n0, h0 = n0, h1 = n0;
#pragma unroll
      for (int j = 0; j < 16; ++j) {
        const int go = ((j * 4 + hi) << 3) ^ aswz;
        const short8 a0v = *reinterpret_cast<const short8*>(LAb + cc * 512 + go);
        const short8 a1v = *reinterpret_cast<const short8*>(LAb + (16 + cc) * 512 + go);
        const short8 bN = *reinterpret_cast<const short8*>(bpN + j * 32);
        const short8 bH = *reinterpret_cast<const short8*>(bpH + j * 32);
        n0 = MFMA(a0v, bN, n0); n1 = MFMA(a1v, bN, n1);
        h0 = MFMA(a0v, bH, h0); h1 = MFMA(a1v, bH, h1);
      }
#pragma unroll
      for (int m = 0; m < 2; ++m) {
        const f32x4 nn = m ? n1 : n0;
        const f32x4 hh = m ? h1 : h0;
#pragma unroll
        for (int q = 0; q < 4; ++q) {
          const int r = m * 16 + hi * 4 + q;
          const int si = r * 512 + ((((col >> 3) ^ (r & 7)) << 3) | (col & 7));
          const float lav = bf2f((ushort_t)LAb[si]);
          float x = nn[q] + XA[(size_t)xr_s[r] * 512 + col];
          x = fminf(fmaxf(x, -12.f), 12.f);
          const float e = __expf(2.f * x);
          const float asv = lav + (e - 1.f) / (e + 1.f);
          const uint_t pz = f2bf(asv);
          const uint_t oz = (uint_t)__shfl_xor((int)pz, 1, 64);
          if (!(cc & 1)) *reinterpret_cast<uint_t*>(ASb + si) = pz | (oz << 16);

          const float hsv = bf2f(HS[((size_t)(b0 + r) * 199 + s) * 512 + col]);
          const float h = fmaxf(hh[q] + hsv + PROJ[(size_t)sk_s[r] * 512 + col], 0.f);
          pv[m][q] = fmaf(h, wo2v[t], pv[m][q]);
        }
      }
    }
    __syncthreads();                  // ASb complete before next step's phase A

    // ---- P reduce + d_out (no sync depends on this) ----
#pragma unroll
    for (int msk = 1; msk < 16; msk <<= 1) {
#pragma unroll
      for (int m = 0; m < 2; ++m)
#pragma unroll
        for (int q = 0; q < 4; ++q) pv[m][q] += __shfl_xor(pv[m][q], msk, 64);
    }
    if (cc == 0) {
#pragma unroll
      for (int m = 0; m < 2; ++m)
#pragma unroll
        for (int q = 0; q < 4; ++q)
          atomicAdd(&d_out[(size_t)(b0 + m * 16 + hi * 4 + q) * 199 + s], pv[m][q]);
    }
  }
}

// ---------------- tail: out = sigmoid(out + b_o2) ----------------
__global__ void rekt_out(float* __restrict__ d_out, const float* __restrict__ b_o2) {
  const int i = blockIdx.x * blockDim.x + threadIdx.x;
  if (i < 512 * 199) {
    const float v = d_out[i] + b_o2[0];
    d_out[i] = 1.f / (1.f + __expf(-v));
  }
}

extern "C" void kernel_launch(void* const* d_in, const int* in_sizes, int n_in,
                              void* d_out, int out_size, void* d_ws, size_t ws_size,
                              hipStream_t stream) {
  const int*   next_skill   = (const int*)d_in[4];
  const int*   next_ans     = (const int*)d_in[5];
  const float* skill_embed  = (const float*)d_in[6];
  const float* ans_embed    = (const float*)d_in[7];
  const float* time_embed   = (const float*)d_in[8];
  const float* ls_state     = (const float*)d_in[9];
  const float* skill_state0 = (const float*)d_in[10];
  const float* W_sf = (const float*)d_in[11];
  const float* b_sf = (const float*)d_in[12];
  const float* W_af = (const float*)d_in[13];
  const float* b_af = (const float*)d_in[14];
  const float* W_ss = (const float*)d_in[15];
  const float* b_ss = (const float*)d_in[16];
  const float* W_as = (const float*)d_in[17];
  const float* b_as = (const float*)d_in[18];
  const float* W_o1 = (const float*)d_in[19];
  const float* b_o1 = (const float*)d_in[20];
  const float* W_o2 = (const float*)d_in[21];
  const float* b_o2 = (const float*)d_in[22];
  float* out = (float*)d_out;
  char*  ws  = (char*)d_ws;

  if (ws_size < WS_NEED) return;

  rekt_prep<<<dim3(2048), dim3(256), 0, stream>>>(
      ls_state, skill_state0, W_sf, W_af, W_ss, W_as, W_o1, out, ws);
  rekt_tab<<<dim3(1701), dim3(512), 0, stream>>>(
      skill_embed, ans_embed, time_embed,
      W_sf, b_sf, W_af, b_af, W_ss, b_ss, W_as, b_as, W_o1, b_o1, ws);
  rekt_idx<<<dim3(512), dim3(64), 0, stream>>>(next_skill, next_ans, ws);
  rekt_lists<<<dim3((NROWS + 255) / 256), dim3(256), 0, stream>>>(ws);

  for (int k = 0; k < ROUNDS; ++k)
    rekt_skill<<<dim3(2048), dim3(512), 0, stream>>>(k, ws);

  rekt_all<<<dim3(16), dim3(512), 0, stream>>>(ls_state, W_o2, out, ws);

  rekt_out<<<dim3((512 * 199 + 255) / 256), dim3(256), 0, stream>>>(out, b_o2);
}

// Round 14
// 3785.296 us; speedup vs baseline: 4.9565x; 4.9565x over previous
//
#include <hip/hip_runtime.h>

typedef unsigned short ushort_t;
typedef unsigned int uint_t;
typedef __attribute__((ext_vector_type(8))) short short8;
typedef __attribute__((ext_vector_type(4))) float f32x4;
typedef __attribute__((ext_vector_type(4))) uint_t uint4v;

// ---------------- workspace layout (bytes) ----------------
constexpr size_t OFF_WSFT  = 0;                          // bf16 [512][512] (n,k): W_sf[k][n], k<512
constexpr size_t OFF_WAFT  = OFF_WSFT  + 512*512*2;      // bf16 [512][512]
constexpr size_t OFF_WO1AT = OFF_WAFT  + 512*512*2;      // bf16 [512][512]  W_o1 rows 0..511
constexpr size_t OFF_WO1BT = OFF_WO1AT + 512*512*2;      // bf16 [512][512]  W_o1 rows 512..1023
constexpr size_t OFF_WAST  = OFF_WO1BT + 512*512*2;      // bf16 [512][512]  W_as top
constexpr size_t OFF_WSST  = OFF_WAST  + 512*512*2;      // bf16 [512][512]  W_ss top
constexpr size_t OFF_GAPS  = OFF_WSST  + 512*512*2;      // f32 [200][512]  te@Wsf_bot + b_sf
constexpr size_t OFF_CAFV  = OFF_GAPS  + 200*512*4;      // f32 [512]       te1@Waf_bot + b_af
constexpr size_t OFF_XA    = OFF_CAFV  + 512*4;          // f32 [600][512]  X@Was_bot + b_as
constexpr size_t OFF_XS    = OFF_XA    + 600*512*4;      // f32 [600][512]  X@Wss_bot + b_ss
constexpr size_t OFF_PROJ  = OFF_XS    + 600*512*4;      // f32 [300][512]  se@Wo1c + b_o1
constexpr size_t OFF_LAG   = OFF_PROJ  + 300*512*4;      // bf16 [512][512] gated last_all
constexpr size_t OFF_LSG   = OFF_LAG   + 512*512*2;      // bf16 [512][512] gated last_sk
constexpr size_t OFF_ASG   = OFF_LSG   + 512*512*2;      // bf16 [512][512] all_state
constexpr size_t OFF_ISKR  = OFF_ASG   + 512*512*2;      // i32 [199][512] gather row
constexpr size_t OFF_IGAP  = OFF_ISKR  + 199*512*4;      // i32 [199][512] gap
constexpr size_t OFF_IXR   = OFF_IGAP  + 199*512*4;      // i32 [199][512] X row
constexpr size_t OFF_ISK   = OFF_IXR   + 199*512*4;      // i32 [199][512] skill
constexpr size_t OFF_BAR   = OFF_ISK   + 199*512*4;      // i32 [32 groups][2 phases][8] flags
constexpr size_t OFF_SKB   = OFF_BAR   + 32*16*4;        // bf16 [512][199][512] skill_buf
constexpr size_t WS_NEED   = OFF_SKB   + (size_t)512*199*512*2;

__device__ __forceinline__ ushort_t f2bf(float f) {
  union { float f; uint_t u; } v; v.f = f;
  uint_t u = v.u;
  return (ushort_t)((u + 0x7FFFu + ((u >> 16) & 1u)) >> 16);
}
__device__ __forceinline__ float bf2f(ushort_t h) {
  union { uint_t u; float f; } v; v.u = ((uint_t)h) << 16;
  return v.f;
}
__device__ __forceinline__ void coh_st4(void* p, uint_t v) {
  __hip_atomic_store((uint_t*)p, v, __ATOMIC_RELAXED, __HIP_MEMORY_SCOPE_AGENT);
}

// ---------------- prologue: transposes + state init ----------------
__global__ void rekt_prep(const float* __restrict__ ls_state, const float* __restrict__ skill_state0,
                          const float* __restrict__ W_sf, const float* __restrict__ W_af,
                          const float* __restrict__ W_ss, const float* __restrict__ W_as,
                          const float* __restrict__ W_o1,
                          float* __restrict__ d_out, char* __restrict__ ws) {
  ushort_t* WSFT  = (ushort_t*)(ws + OFF_WSFT);
  ushort_t* WAFT  = (ushort_t*)(ws + OFF_WAFT);
  ushort_t* WO1AT = (ushort_t*)(ws + OFF_WO1AT);
  ushort_t* WO1BT = (ushort_t*)(ws + OFF_WO1BT);
  ushort_t* WAST  = (ushort_t*)(ws + OFF_WAST);
  ushort_t* WSST  = (ushort_t*)(ws + OFF_WSST);
  ushort_t* ASG   = (ushort_t*)(ws + OFF_ASG);
  int*      BARp  = (int*)(ws + OFF_BAR);
  ushort_t* SKB   = (ushort_t*)(ws + OFF_SKB);

  const size_t t0 = (size_t)blockIdx.x * blockDim.x + threadIdx.x;
  const size_t st = (size_t)gridDim.x * blockDim.x;

  for (size_t i = t0; i < 512*512; i += st) {
    const int k = (int)(i >> 9), n = (int)(i & 511);
    const size_t d = (size_t)n * 512 + k;
    WSFT[d]  = f2bf(W_sf[i]);
    WAFT[d]  = f2bf(W_af[i]);
    WAST[d]  = f2bf(W_as[i]);
    WSST[d]  = f2bf(W_ss[i]);
    WO1AT[d] = f2bf(W_o1[i]);
    WO1BT[d] = f2bf(W_o1[i + (size_t)512*512]);
  }
  for (size_t i = t0; i < 512*512; i += st) ASG[i] = f2bf(ls_state[i & 511]);
  for (size_t i = t0; i < 512*512; i += st) {
    const size_t b = i >> 9, n = i & 511;
    SKB[(b * 199) * 512 + n] = f2bf(skill_state0[n]);
  }
  for (size_t i = t0; i < 512*199; i += st) d_out[i] = 0.f;
  for (size_t i = t0; i < 32*16; i += st) BARp[i] = 0;
}

// ---------------- tables: XA/XS/PROJ/GAPS/CAF ----------------
__global__ void rekt_tab(const float* __restrict__ se, const float* __restrict__ ae,
                         const float* __restrict__ te,
                         const float* __restrict__ W_sf, const float* __restrict__ b_sf,
                         const float* __restrict__ W_af, const float* __restrict__ b_af,
                         const float* __restrict__ W_ss, const float* __restrict__ b_ss,
                         const float* __restrict__ W_as, const float* __restrict__ b_as,
                         const float* __restrict__ W_o1, const float* __restrict__ b_o1,
                         char* __restrict__ ws) {
  __shared__ float ar[512];
  const int n = threadIdx.x;
  const int bid = blockIdx.x;
  const float* W; const float* bias; float* dst;
  if (bid < 600) {
    const int a = bid / 300, sk = bid % 300;
    ar[n] = se[(size_t)sk*512 + n] + ae[(size_t)a*512 + n];
    W = W_as + (size_t)512*512; bias = b_as; dst = (float*)(ws + OFF_XA) + (size_t)bid*512;
  } else if (bid < 1200) {
    const int r = bid - 600, a = r / 300, sk = r % 300;
    ar[n] = se[(size_t)sk*512 + n] + ae[(size_t)a*512 + n];
    W = W_ss + (size_t)512*512; bias = b_ss; dst = (float*)(ws + OFF_XS) + (size_t)r*512;
  } else if (bid < 1500) {
    const int r = bid - 1200;
    ar[n] = se[(size_t)r*512 + n];
    W = W_o1 + (size_t)1024*512; bias = b_o1; dst = (float*)(ws + OFF_PROJ) + (size_t)r*512;
  } else if (bid < 1700) {
    const int t = bid - 1500;
    ar[n] = te[(size_t)t*512 + n];
    W = W_sf + (size_t)512*512; bias = b_sf; dst = (float*)(ws + OFF_GAPS) + (size_t)t*512;
  } else {
    ar[n] = te[512 + n];
    W = W_af + (size_t)512*512; bias = b_af; dst = (float*)(ws + OFF_CAFV);
  }
  __syncthreads();
  float acc = bias[n];
  for (int k = 0; k < 512; ++k) acc = fmaf(ar[k], W[(size_t)k*512 + n], acc);
  dst[n] = acc;
}

// ---------------- per-step index precompute ----------------
__global__ void rekt_idx(const int* __restrict__ next_skill, const int* __restrict__ next_ans,
                         char* __restrict__ ws) {
  int* ISKR = (int*)(ws + OFF_ISKR);
  int* IGAP = (int*)(ws + OFF_IGAP);
  int* IXR  = (int*)(ws + OFF_IXR);
  int* ISK  = (int*)(ws + OFF_ISK);
  __shared__ int lt[300];
  const int b = blockIdx.x;
  for (int i = threadIdx.x; i < 300; i += blockDim.x) lt[i] = 0;
  __syncthreads();
  if (threadIdx.x == 0) {
    for (int s = 0; s < 199; ++s) {
      const int sk = next_skill[b * 199 + s];
      const int tl = lt[sk];
      ISKR[s * 512 + b] = b * 199 + tl;
      IGAP[s * 512 + b] = s - tl;
      IXR [s * 512 + b] = next_ans[b * 199 + s] * 300 + sk;
      ISK [s * 512 + b] = sk;
      lt[sk] = s;
    }
  }
}

// ---------------- flag barrier: parallel stores, 8-lane poll ----------------
__device__ __forceinline__ void bar_sig(int* flg, int sl, int val) {
  __syncthreads();                    // drains every wave's vm stores (vmcnt 0) first
  if (threadIdx.x == 0)
    __hip_atomic_store(flg + sl, val, __ATOMIC_RELAXED, __HIP_MEMORY_SCOPE_AGENT);
}
__device__ __forceinline__ void bar_wait(const int* flg, int val) {
  if (threadIdx.x < 8) {
    int guard = 0;
    while (__hip_atomic_load(flg + threadIdx.x, __ATOMIC_RELAXED, __HIP_MEMORY_SCOPE_AGENT) < val) {
      __builtin_amdgcn_s_sleep(1);
      if (++guard > (1 << 22)) break;  // fail loud (bad absmax), never hang
    }
  }
  __syncthreads();
}

// ---------------- staging: 2x (16 rows x 512 bf16) via 16B sc0sc1 loads, batched ----------------
template<bool GATHER>
__device__ __forceinline__ void stage2(short* Ta, short* Tb,
                                       const ushort_t* __restrict__ baseA, const int* rowsA,
                                       const ushort_t* __restrict__ baseB, int b0, int tid) {
  uint4v va[2], vb[2];
  int dst[2];
#pragma unroll
  for (int t = 0; t < 2; ++t) {
    const int i = t * 512 + tid;
    const int r = i >> 6, gi = i & 63;
    const size_t rowA = GATHER ? (size_t)rowsA[r] : (size_t)(b0 + r);
    const ushort_t* pa = baseA + rowA * 512 + gi * 8;
    const ushort_t* pb = baseB + (size_t)(b0 + r) * 512 + gi * 8;
    asm volatile("global_load_dwordx4 %0, %1, off sc0 sc1" : "=v"(va[t]) : "v"(pa));
    asm volatile("global_load_dwordx4 %0, %1, off sc0 sc1" : "=v"(vb[t]) : "v"(pb));
    dst[t] = r * 512 + ((gi ^ (r & 7)) << 3);
  }
  asm volatile("s_waitcnt vmcnt(0)" ::: "memory");
  __builtin_amdgcn_sched_barrier(0);
#pragma unroll
  for (int t = 0; t < 2; ++t) {
    *reinterpret_cast<uint4v*>(Ta + dst[t]) = va[t];
    *reinterpret_cast<uint4v*>(Tb + dst[t]) = vb[t];
  }
}

#define MFMA(a, b, c) __builtin_amdgcn_mfma_f32_16x16x32_bf16((a), (b), (c), 0, 0, 0)

// ---------------- main scan ----------------
// 256 blocks = 32 groups (16 batches, M=16) x 8 N-slices (64 cols).  512 thr = 8 waves:
// wave w: nt = w&3 (16-col tile), set = w>>2 (0:{fa,ha,na} 1:{ga,hb,ns}).
// Halved barrier fan-in (8) and stage volume (16KB/phase) vs round-10's 16x16 geometry.
__global__ __launch_bounds__(512, 1) void rekt_main(
    const float* __restrict__ w_o2,
    float* __restrict__ d_out, char* __restrict__ ws) {

  const ushort_t* WSFT  = (const ushort_t*)(ws + OFF_WSFT);
  const ushort_t* WAFT  = (const ushort_t*)(ws + OFF_WAFT);
  const ushort_t* WO1AT = (const ushort_t*)(ws + OFF_WO1AT);
  const ushort_t* WO1BT = (const ushort_t*)(ws + OFF_WO1BT);
  const ushort_t* WAST  = (const ushort_t*)(ws + OFF_WAST);
  const ushort_t* WSST  = (const ushort_t*)(ws + OFF_WSST);
  const float* GAPS = (const float*)(ws + OFF_GAPS);
  const float* CAFV = (const float*)(ws + OFF_CAFV);
  const float* XA   = (const float*)(ws + OFF_XA);
  const float* XS   = (const float*)(ws + OFF_XS);
  const float* PROJ = (const float*)(ws + OFF_PROJ);
  ushort_t* LAG = (ushort_t*)(ws + OFF_LAG);
  ushort_t* LSG = (ushort_t*)(ws + OFF_LSG);
  ushort_t* ASG = (ushort_t*)(ws + OFF_ASG);
  const int* ISKR = (const int*)(ws + OFF_ISKR);
  const int* IGAP = (const int*)(ws + OFF_IGAP);
  const int* IXR  = (const int*)(ws + OFF_IXR);
  const int* ISK  = (const int*)(ws + OFF_ISK);
  int*      FLG = (int*)(ws + OFF_BAR);
  ushort_t* SKB = (ushort_t*)(ws + OFF_SKB);

  __shared__ __align__(16) short Ta[16 * 512];
  __shared__ __align__(16) short Tb[16 * 512];
  __shared__ float Hbuf[16 * 68];
  __shared__ int sk_s[16], gap_s[16], xr_s[16], skrow_s[16];

  const int tid = threadIdx.x;
  const int lane = tid & 63, w = tid >> 6;
  const int cc = lane & 15, hi = lane >> 4;
  const int nt = w & 3, setB = w >> 2;
  const int g = blockIdx.x >> 3, sl = blockIdx.x & 7;
  const int b0 = g << 4;
  const int nc = sl * 64 + nt * 16 + cc;       // this lane's output column
  const int ncl = nt * 16 + cc;                // block-local column (0..63)
  const int r0 = hi << 2;                      // acc row base (4 rows; M=16)
  const int aswz = (cc & 7) << 3;
  int* flgA = FLG + g * 16;
  int* flgB = flgA + 8;

  const float cafv = CAFV[nc];
  const float wo2v = w_o2[nc];

  // set-split B-operand column pointers ([n][k] layout)
  const ushort_t* BA = (setB ? WAFT  : WSFT ) + (size_t)nc * 512 + hi * 8;
  const ushort_t* BH = (setB ? WO1BT : WO1AT) + (size_t)nc * 512 + hi * 8;
  const ushort_t* BU = (setB ? WSST  : WAST ) + (size_t)nc * 512 + hi * 8;

  for (int s = 0; s < 199; ++s) {
    // ---- index fill + phase-A frag prefetch: both independent of the barrier ----
    if (tid < 16) {
      const int o = s * 512 + b0 + tid;
      sk_s[tid]    = ISK[o];
      gap_s[tid]   = IGAP[o];
      xr_s[tid]    = IXR[o];
      skrow_s[tid] = ISKR[o];
    }
    short8 Bf[16];
#pragma unroll
    for (int j = 0; j < 16; ++j) Bf[j] = *reinterpret_cast<const short8*>(BA + j * 32);

    bar_wait(flgB, s);                         // prev step's AS/SKB visible (also publishes sk_s)

    // ---- stage: Ta = SKg (gather), Tb = AS ----
    stage2<true>(Ta, Tb, SKB, skrow_s, ASG, b0, tid);
    __syncthreads();

    // ---- phase A: set0 fa = SKg@Wsf ; set1 ga = AS@Waf ----
    f32x4 accA = {0.f, 0.f, 0.f, 0.f};
    {
      const short* a0 = (setB ? Tb : Ta) + cc * 512;
#pragma unroll
      for (int j = 0; j < 16; ++j) {
        const short8 a = *reinterpret_cast<const short8*>(a0 + (((j * 4 + hi) << 3) ^ aswz));
        accA = MFMA(a, Bf[j], accA);
      }
    }

    // ---- epilogue A ----
    if (setB == 0) {                            // LS = SKg * sigmoid(fa + GAPS[gap])
#pragma unroll
      for (int q = 0; q < 4; ++q) {
        const int r = r0 + q;
        const float F = accA[q] + GAPS[(size_t)gap_s[r] * 512 + nc];
        const float sg = 1.f / (1.f + __expf(-F));
        const float skg = bf2f((ushort_t)Ta[r * 512 + (((nc >> 3) ^ (r & 7)) << 3) + (nc & 7)]);
        const uint_t pz = f2bf(skg * sg);
        const uint_t oz = (uint_t)__shfl_xor((int)pz, 1, 64);
        if (!(cc & 1)) coh_st4(LSG + (size_t)(b0 + r) * 512 + nc, pz | (oz << 16));
      }
    } else {                                    // LA = AS * sigmoid(ga + CAF)
#pragma unroll
      for (int q = 0; q < 4; ++q) {
        const int r = r0 + q;
        const float G = accA[q] + cafv;
        const float sg = 1.f / (1.f + __expf(-G));
        const float asv = bf2f((ushort_t)Tb[r * 512 + (((nc >> 3) ^ (r & 7)) << 3) + (nc & 7)]);
        const uint_t pz = f2bf(asv * sg);
        const uint_t oz = (uint_t)__shfl_xor((int)pz, 1, 64);
        if (!(cc & 1)) coh_st4(LAG + (size_t)(b0 + r) * 512 + nc, pz | (oz << 16));
      }
    }
    bar_sig(flgA, sl, s + 1);

    // ---- phase-B frag prefetch while others arrive ----
    short8 B1[16], B2[16];
#pragma unroll
    for (int j = 0; j < 16; ++j) {
      B1[j] = *reinterpret_cast<const short8*>(BH + j * 32);
      B2[j] = *reinterpret_cast<const short8*>(BU + j * 32);
    }
    bar_wait(flgA, s + 1);                     // all slices' LA/LS visible

    // ---- stage: Ta = LA, Tb = LS ----
    stage2<false>(Ta, Tb, LAG, nullptr, LSG, b0, tid);
    __syncthreads();

    // ---- phase B: set0 {ha, na} from LA ; set1 {hb, ns} from LS ----
    f32x4 acc1 = {0.f, 0.f, 0.f, 0.f}, acc2 = {0.f, 0.f, 0.f, 0.f};
    {
      const short* a0 = (setB ? Tb : Ta) + cc * 512;
#pragma unroll
      for (int j = 0; j < 16; ++j) {
        const short8 a = *reinterpret_cast<const short8*>(a0 + (((j * 4 + hi) << 3) ^ aswz));
        acc1 = MFMA(a, B1[j], acc1);
        acc2 = MFMA(a, B2[j], acc2);
      }
    }

    // ---- epilogue B ----
    if (setB == 0) {                            // publish ha partial
#pragma unroll
      for (int q = 0; q < 4; ++q) Hbuf[(r0 + q) * 68 + ncl] = acc1[q];
    }
    __syncthreads();

    float pv[4];
    if (setB == 0) {                            // AS' = LA + tanh(na + XA[xr])
#pragma unroll
      for (int q = 0; q < 4; ++q) {
        const int r = r0 + q;
        float x = acc2[q] + XA[(size_t)xr_s[r] * 512 + nc];
        x = fminf(fmaxf(x, -12.f), 12.f);
        const float e = __expf(2.f * x);
        const float lav = bf2f((ushort_t)Ta[r * 512 + (((nc >> 3) ^ (r & 7)) << 3) + (nc & 7)]);
        const uint_t pz = f2bf(lav + (e - 1.f) / (e + 1.f));
        const uint_t oz = (uint_t)__shfl_xor((int)pz, 1, 64);
        if (!(cc & 1)) coh_st4(ASG + (size_t)(b0 + r) * 512 + nc, pz | (oz << 16));
      }
    } else {                                    // P partial (kept in regs) + SK' = LS + tanh(ns + XS)
#pragma unroll
      for (int q = 0; q < 4; ++q) {
        const int r = r0 + q;
        const float h = fmaxf(Hbuf[r * 68 + ncl] + acc1[q] + PROJ[(size_t)sk_s[r] * 512 + nc], 0.f);
        pv[q] = h * wo2v;

        float y = acc2[q] + XS[(size_t)xr_s[r] * 512 + nc];
        y = fminf(fmaxf(y, -12.f), 12.f);
        const float e = __expf(2.f * y);
        const float lsv = bf2f((ushort_t)Tb[r * 512 + (((nc >> 3) ^ (r & 7)) << 3) + (nc & 7)]);
        const uint_t pz = f2bf(lsv + (e - 1.f) / (e + 1.f));
        const uint_t oz = (uint_t)__shfl_xor((int)pz, 1, 64);
        if (!(cc & 1)) coh_st4(SKB + ((size_t)(b0 + r) * 199 + s) * 512 + nc, pz | (oz << 16));
      }
    }
    bar_sig(flgB, sl, s + 1);

    // ---- post-signal: P reduction + d_out atomic (off the critical path) ----
    if (setB == 1) {
#pragma unroll
      for (int msk = 1; msk < 16; msk <<= 1) {
#pragma unroll
        for (int q = 0; q < 4; ++q) pv[q] += __shfl_xor(pv[q], msk, 64);
      }
      if (cc == 0) {
#pragma unroll
        for (int q = 0; q < 4; ++q) atomicAdd(&d_out[(size_t)(b0 + r0 + q) * 199 + s], pv[q]);
      }
    }
  }
}

// ---------------- tail: out = sigmoid(out + b_o2) ----------------
__global__ void rekt_out(float* __restrict__ d_out, const float* __restrict__ b_o2) {
  const int i = blockIdx.x * blockDim.x + threadIdx.x;
  if (i < 512 * 199) {
    const float v = d_out[i] + b_o2[0];
    d_out[i] = 1.f / (1.f + __expf(-v));
  }
}

extern "C" void kernel_launch(void* const* d_in, const int* in_sizes, int n_in,
                              void* d_out, int out_size, void* d_ws, size_t ws_size,
                              hipStream_t stream) {
  const int*   next_skill   = (const int*)d_in[4];
  const int*   next_ans     = (const int*)d_in[5];
  const float* skill_embed  = (const float*)d_in[6];
  const float* ans_embed    = (const float*)d_in[7];
  const float* time_embed   = (const float*)d_in[8];
  const float* ls_state     = (const float*)d_in[9];
  const float* skill_state0 = (const float*)d_in[10];
  const float* W_sf = (const float*)d_in[11];
  const float* b_sf = (const float*)d_in[12];
  const float* W_af = (const float*)d_in[13];
  const float* b_af = (const float*)d_in[14];
  const float* W_ss = (const float*)d_in[15];
  const float* b_ss = (const float*)d_in[16];
  const float* W_as = (const float*)d_in[17];
  const float* b_as = (const float*)d_in[18];
  const float* W_o1 = (const float*)d_in[19];
  const float* b_o1 = (const float*)d_in[20];
  const float* W_o2 = (const float*)d_in[21];
  const float* b_o2 = (const float*)d_in[22];
  float* out = (float*)d_out;
  char*  ws  = (char*)d_ws;

  if (ws_size < WS_NEED) return;

  rekt_prep<<<dim3(2048), dim3(256), 0, stream>>>(
      ls_state, skill_state0, W_sf, W_af, W_ss, W_as, W_o1, out, ws);
  rekt_tab<<<dim3(1701), dim3(512), 0, stream>>>(
      skill_embed, ans_embed, time_embed,
      W_sf, b_sf, W_af, b_af, W_ss, b_ss, W_as, b_as, W_o1, b_o1, ws);
  rekt_idx<<<dim3(512), dim3(64), 0, stream>>>(next_skill, next_ans, ws);

  rekt_main<<<dim3(256), dim3(512), 0, stream>>>(W_o2, out, ws);

  rekt_out<<<dim3((512 * 199 + 255) / 256), dim3(256), 0, stream>>>(out, b_o2);
}